// Round 5
// baseline (164.956 us; speedup 1.0000x reference)
//
#include <hip/hip_runtime.h>

// LRU linear recurrence, fused, MFMA + wave-specialized pipeline (round-4 base).
// Round-5 changes (de-stall):
//  (a) raw s_barrier + lgkmcnt(0)-only waits in the main loop (no vmcnt(0)
//      drain of Y-stores / U-prefetch at barriers).
//  (b) Y-MFMA accumulator chains split 2 -> 4 (12-deep, 4-way ILP).
//  (c) bu stored as interleaved (re,im) pairs -> recurrence batch-loads 16
//      ds_read_b64 into registers before the serial chain.
//  (d) xs bf16 hi/lo packing via v_cvt_pk_bf16_f32 (RNE), ~6 fewer VALU/step.

constexpr int NY  = 64;
constexpr int NU  = 32;
constexpr int NH  = 512;
constexpr int NH2 = 256;
constexpr int TT  = 512;
constexpr int BB  = 256;
constexpr int KK  = 16;
constexpr int NSS = TT / KK;     // 32

constexpr int USP = 40;          // us row pitch (shorts)
constexpr int XSP = 544;         // xs row pitch (shorts), word pitch 272 = 16 (mod 32)
constexpr int BUP = 516;         // bu row pitch (f32 words), interleaved (re,im)
constexpr int PSP = 20;          // psy last-dim pitch (f32)

typedef __attribute__((ext_vector_type(4))) short sh4;
typedef __attribute__((ext_vector_type(8))) short sh8;
typedef __attribute__((ext_vector_type(4))) float f32x4;

#define MFMA16(a, b, c) __builtin_amdgcn_mfma_f32_16x16x32_bf16((a), (b), (c), 0, 0, 0)

static __device__ __forceinline__ unsigned short bfh(float x) {
    return (unsigned short)(__float_as_uint(x) >> 16);
}
static __device__ __forceinline__ float bf2f(unsigned short h) {
    return __uint_as_float(((unsigned)h) << 16);
}
static __device__ __forceinline__ void cvt4(const float4 f, sh4& vh, sh4& vl) {
    const float e[4] = { f.x, f.y, f.z, f.w };
#pragma unroll
    for (int j = 0; j < 4; ++j) {
        const unsigned short h = bfh(e[j]);
        vh[j] = (short)h;
        vl[j] = (short)bfh(e[j] - bf2f(h));
    }
}
// pack two f32 -> (bf16(a) | bf16(b)<<16), RNE
static __device__ __forceinline__ unsigned cvtpk(float a, float b) {
    unsigned r;
    asm("v_cvt_pk_bf16_f32 %0, %1, %2" : "=v"(r) : "v"(a), "v"(b));
    return r;
}
static __device__ __forceinline__ void xs_store(unsigned* xh, unsigned* xl, int idx,
                                                float xr, float xi) {
    const unsigned hp = cvtpk(xr, xi);
    const float rr = __uint_as_float(hp << 16);
    const float ri = __uint_as_float(hp & 0xffff0000u);
    xh[idx] = hp;
    xl[idx] = cvtpk(xr - rr, xi - ri);
}
// LDS-only barrier: waits ds ops, does NOT drain vmcnt (global stores/prefetch).
static __device__ __forceinline__ void bar_lds() {
    __builtin_amdgcn_sched_barrier(0);
    asm volatile("s_waitcnt lgkmcnt(0)" ::: "memory");
    __builtin_amdgcn_s_barrier();
    __builtin_amdgcn_sched_barrier(0);
}

__global__ __launch_bounds__(512, 2)
void lru_fused_kernel(const float* __restrict__ y0,     // [BB][NY]
                      const float* __restrict__ U,      // [TT][BB][NU]
                      const float* __restrict__ lmr,    // [NH2]
                      const float* __restrict__ lmi,    // [NH2]
                      const float* __restrict__ Bmat,   // [NH][NU]
                      const float* __restrict__ Wy2x,   // [NH][NY]
                      const float* __restrict__ by2x,   // [NH]
                      const float* __restrict__ Wx2y,   // [NY][NH]
                      const float* __restrict__ bx2y,   // [NY]
                      float* __restrict__ Y)            // [TT+1][BB][NY]
{
    const int b    = blockIdx.x;
    const int tid  = threadIdx.x;
    const int w    = tid >> 6;     // wave 0..7
    const int l    = tid & 63;
    const int lr16 = l & 15;       // MFMA A-row / B-col / D-col
    const int lg   = l >> 4;       // MFMA lane group

    __shared__ unsigned short us_h[2][64][USP], us_l[2][64][USP];   // permuted U
    __shared__ unsigned short xs_h[2][KK][XSP], xs_l[2][KK][XSP];   // dbuf, permuted X
    __shared__ float          bu[KK][BUP];                          // Bu (re,im) pairs
    __shared__ float          psy[4][2][16][PSP];                   // Y k-half partials
    __shared__ float          y0s[NY];

    // frg: register fragment pool, UNIONED between roles.
    // front: frg[0..7]=B hi (q), frg[8..15]=B lo.
    // back : frg[ntt*8+ks]=W hi, frg[16+ntt*8+ks]=W lo.
    sh8 frg[32];
    float lamr = 0.f, lami = 0.f, xr = 0.f, xi = 0.f;
    float biasE = 0.f;
    int   xwrd  = 0;

    if (tid < NH2) {
        // ---- front: B fragments (wave w owns hidden [w*128, w*128+128)) ----
#pragma unroll
        for (int q = 0; q < 8; ++q) {
            sh8 vh, vl;
#pragma unroll
            for (int h2 = 0; h2 < 2; ++h2) {
                const int hrow = (w << 7) + (q << 4) + lr16;
                const int u0   = (h2 << 4) + (lg << 2);
                const float4 f4 = *reinterpret_cast<const float4*>(&Bmat[hrow * NU + u0]);
                sh4 th, tl;
                cvt4(f4, th, tl);
#pragma unroll
                for (int j = 0; j < 4; ++j) { vh[h2 * 4 + j] = th[j]; vl[h2 * 4 + j] = tl[j]; }
            }
            frg[q] = vh;
            frg[8 + q] = vl;
        }
        lamr = lmr[tid];
        lami = lmi[tid];
        const int q_ = tid & 15, blk = tid >> 4;
        xwrd = blk * 16 + ((q_ & 7) >> 1) * 4 + (q_ >> 3) * 2 + (q_ & 1);
    } else {
        // ---- back: W fragments for (nt-pair ntp, k-half kh) ----
        const int j = w - 4, ntp = j >> 1, kh = j & 1;
#pragma unroll
        for (int ntt = 0; ntt < 2; ++ntt) {
            const int n = ((ntp << 1) + ntt) * 16 + lr16;
            const float* Wn = Wx2y + n * NH;
#pragma unroll
            for (int ks = 0; ks < 8; ++ks) {
                sh8 vh, vl;
#pragma unroll
                for (int h2 = 0; h2 < 2; ++h2) {
                    const int k0 = (kh << 8) + (ks << 5) + (h2 << 4) + (lg << 2);
                    const int p0 = k0 >> 1;
                    const float e[4] = { Wn[p0], Wn[p0 + 256], Wn[p0 + 1], Wn[p0 + 257] };
#pragma unroll
                    for (int j2 = 0; j2 < 4; ++j2) {
                        const unsigned short h = bfh(e[j2]);
                        vh[h2 * 4 + j2] = (short)h;
                        vl[h2 * 4 + j2] = (short)bfh(e[j2] - bf2f(h));
                    }
                }
                frg[ntt * 8 + ks] = vh;
                frg[16 + ntt * 8 + ks] = vl;
            }
        }
        biasE = bx2y[(j << 4) + lr16];
    }

    // ---- stage U chunk 0 (permuted bf16 hi/lo), all 512 threads ----
    const float4* Ug = reinterpret_cast<const float4*>(U);
    {
        const int i = tid, t = i >> 3, g = i & 7;
        const float4 f = Ug[((t * BB + b) << 3) + g];
        const int pos = (g < 4) ? (g << 3) : (((g - 4) << 3) + 4);
        sh4 vh, vl;
        cvt4(f, vh, vl);
        *reinterpret_cast<sh4*>(&us_h[0][t][pos]) = vh;
        *reinterpret_cast<sh4*>(&us_l[0][t][pos]) = vl;
    }
    if (tid < NY) y0s[tid] = y0[b * NY + tid];
    __syncthreads();

    // ---- prologue: x0 (fp32) -> xs slot 1, row 0 ----
    if (tid < NH2) {
        const float* wr = &Wy2x[tid * NY];
        const float* wi = &Wy2x[(NH2 + tid) * NY];
        float a0 = 0, a1 = 0, a2 = 0, a3 = 0;
        float c0 = 0, c1 = 0, c2 = 0, c3 = 0;
#pragma unroll
        for (int y = 0; y < NY; y += 4) {
            a0 += wr[y + 0] * y0s[y + 0];
            a1 += wr[y + 1] * y0s[y + 1];
            a2 += wr[y + 2] * y0s[y + 2];
            a3 += wr[y + 3] * y0s[y + 3];
            c0 += wi[y + 0] * y0s[y + 0];
            c1 += wi[y + 1] * y0s[y + 1];
            c2 += wi[y + 2] * y0s[y + 2];
            c3 += wi[y + 3] * y0s[y + 3];
        }
        xr = by2x[tid]       + (a0 + a1) + (a2 + a3);
        xi = by2x[NH2 + tid] + (c0 + c1) + (c2 + c3);
        xs_store(reinterpret_cast<unsigned*>(&xs_h[1][0][0]),
                 reinterpret_cast<unsigned*>(&xs_l[1][0][0]), xwrd, xr, xi);
    }
    __syncthreads();

    float4 pf0, pf1;   // U prefetch staging (back waves)

    // ============================ main loop ============================
    for (int st = 0; st <= NSS; ++st) {
        // =============== phase alpha ===============
        if (tid < NH2) {
            if (st < NSS) {   // B: Bu = U(16x32) . B^T(32x512)
                const int su = (st >> 2) & 1, t0 = (st & 3) << 4;
                const sh8 auh = *reinterpret_cast<const sh8*>(&us_h[su][t0 + lr16][lg << 3]);
                const sh8 aul = *reinterpret_cast<const sh8*>(&us_l[su][t0 + lr16][lg << 3]);
#pragma unroll
                for (int q = 0; q < 8; ++q) {
                    f32x4 acc = (f32x4){0.f, 0.f, 0.f, 0.f};
                    acc = MFMA16(auh, frg[q], acc);
                    acc = MFMA16(aul, frg[q], acc);
                    acc = MFMA16(auh, frg[8 + q], acc);
                    const int h = (w << 7) + (q << 4) + lr16;
                    const int c = (h < NH2) ? (h << 1) : (((h - NH2) << 1) | 1);
#pragma unroll
                    for (int r = 0; r < 4; ++r)
                        bu[(lg << 2) + r][c] = acc[r];
                }
            }
        } else {
            const int cc = st >> 2;
            if ((st & 3) == 0 && cc < 7 && st < NSS) {   // prefetch issue
                const int i0 = tid - NH2, i1 = tid;
                pf0 = Ug[(((((cc + 1) << 6) + (i0 >> 3)) * BB + b) << 3) + (i0 & 7)];
                pf1 = Ug[(((((cc + 1) << 6) + (i1 >> 3)) * BB + b) << 3) + (i1 & 7)];
            }
            // D: Y partial = X(16x256-half) . W^T, 4 independent acc chains
            const int sx = (st + 1) & 1;
            const int j = w - 4, kh = j & 1;
            f32x4 a0a = (f32x4){0.f, 0.f, 0.f, 0.f};
            f32x4 a1a = (f32x4){0.f, 0.f, 0.f, 0.f};
            f32x4 a0b = (f32x4){0.f, 0.f, 0.f, 0.f};
            f32x4 a1b = (f32x4){0.f, 0.f, 0.f, 0.f};
#pragma unroll
            for (int ks = 0; ks < 4; ++ks) {
                const int sp = (kh << 8) + (ks << 5) + (lg << 3);
                const sh8 axh = *reinterpret_cast<const sh8*>(&xs_h[sx][lr16][sp]);
                const sh8 axl = *reinterpret_cast<const sh8*>(&xs_l[sx][lr16][sp]);
                a0a = MFMA16(axh, frg[ks], a0a);
                a0a = MFMA16(axl, frg[ks], a0a);
                a0a = MFMA16(axh, frg[16 + ks], a0a);
                a1a = MFMA16(axh, frg[8 + ks], a1a);
                a1a = MFMA16(axl, frg[8 + ks], a1a);
                a1a = MFMA16(axh, frg[24 + ks], a1a);
            }
#pragma unroll
            for (int ks = 4; ks < 8; ++ks) {
                const int sp = (kh << 8) + (ks << 5) + (lg << 3);
                const sh8 axh = *reinterpret_cast<const sh8*>(&xs_h[sx][lr16][sp]);
                const sh8 axl = *reinterpret_cast<const sh8*>(&xs_l[sx][lr16][sp]);
                a0b = MFMA16(axh, frg[ks], a0b);
                a0b = MFMA16(axl, frg[ks], a0b);
                a0b = MFMA16(axh, frg[16 + ks], a0b);
                a1b = MFMA16(axh, frg[8 + ks], a1b);
                a1b = MFMA16(axl, frg[8 + ks], a1b);
                a1b = MFMA16(axh, frg[24 + ks], a1b);
            }
            const f32x4 A0 = a0a + a0b;
            const f32x4 A1 = a1a + a1b;
#pragma unroll
            for (int r = 0; r < 4; ++r) {
                psy[j][0][(lg << 2) + r][lr16] = A0[r];
                psy[j][1][(lg << 2) + r][lr16] = A1[r];
            }
        }
        bar_lds();   // barA: bu + psy visible (LDS only)

        // =============== phase beta ===============
        if (tid < NH2) {
            if (st < NSS) {   // C: serial recurrence, batch-loaded bu pairs
                const int sw = st & 1;
                unsigned* xh = reinterpret_cast<unsigned*>(&xs_h[sw][0][0]);
                unsigned* xl = reinterpret_cast<unsigned*>(&xs_l[sw][0][0]);
                float2 bu2[KK];
#pragma unroll
                for (int k = 0; k < KK; ++k)
                    bu2[k] = *reinterpret_cast<const float2*>(&bu[k][tid << 1]);
#pragma unroll
                for (int k = 0; k < KK; ++k) {
                    const float nr = lamr * xr - lami * xi + bu2[k].x;
                    const float ni = lami * xr + lamr * xi + bu2[k].y;
                    xr = nr;
                    xi = ni;
                    xs_store(xh, xl, k * (XSP / 2) + xwrd, xr, xi);
                }
            }
        } else {
            if ((st & 3) == 1 && (st >> 2) < 7) {   // prefetch commit
                const int ns = ((st >> 2) + 1) & 1;
#pragma unroll
                for (int v = 0; v < 2; ++v) {
                    const float4 f = v ? pf1 : pf0;
                    const int i = v ? tid : (tid - NH2);
                    const int t = i >> 3, g = i & 7;
                    const int pos = (g < 4) ? (g << 3) : (((g - 4) << 3) + 4);
                    sh4 vh, vl;
                    cvt4(f, vh, vl);
                    *reinterpret_cast<sh4*>(&us_h[ns][t][pos]) = vh;
                    *reinterpret_cast<sh4*>(&us_l[ns][t][pos]) = vl;
                }
            }
            // E: pair-reduce psy + store. Wave 4+j handles nt = j.
            const int j = w - 4;
            const int j0 = j & ~1;
#pragma unroll
            for (int r = 0; r < 4; ++r) {
                const int m = (lg << 2) + r;
                const float v = psy[j0][j & 1][m][lr16] + psy[j0 + 1][j & 1][m][lr16] + biasE;
                if (st == 0) {
                    if (m == 0) Y[b * NY + (j << 4) + lr16] = v;
                } else {
                    const int s = ((st - 1) << 4) + m + 1;
                    Y[(s * BB + b) * NY + (j << 4) + lr16] = v;
                }
            }
        }
        bar_lds();   // barB: xs + us visible (LDS only)
    }
}

extern "C" void kernel_launch(void* const* d_in, const int* in_sizes, int n_in,
                              void* d_out, int out_size, void* d_ws, size_t ws_size,
                              hipStream_t stream) {
    const float* y0   = (const float*)d_in[0];
    const float* U    = (const float*)d_in[1];
    const float* lmr  = (const float*)d_in[2];
    const float* lmi  = (const float*)d_in[3];
    const float* Bm   = (const float*)d_in[4];
    const float* Wy2x = (const float*)d_in[5];
    const float* by2x = (const float*)d_in[6];
    const float* Wx2y = (const float*)d_in[7];
    const float* bx2y = (const float*)d_in[8];
    float* Y = (float*)d_out;

    lru_fused_kernel<<<dim3(BB), dim3(512), 0, stream>>>(
        y0, U, lmr, lmi, Bm, Wy2x, by2x, Wx2y, bx2y, Y);
}